// Round 7
// baseline (5711.938 us; speedup 1.0000x reference)
//
#include <hip/hip_runtime.h>
#include <math.h>

#define TT 512
#define BB 64
#define DIN 256
#define HH 512
#define DOUT 256

// f16 row stride: 776 f16 = 388 u32 (16B-aligned rows)
#define RSU 388          // row stride in u32
#define RSH 776          // row stride in f16

// LDS layout (u32 units)
#define W_HI_OFF 0
#define W_LO_OFF 12416   // 32*388
#define A_HI_OFF 24832
#define A_LO_OFF 31040   // +16*388
#define P_OFF    37248   // 4 tiles * 320 floats
#define B_OFF    38528   // 32 biases
#define C_OFF    38560   // 128 cell states
#define HST_HI   38688   // 64 u32 (128 u16) h-hi stage
#define HST_LO   38752   // 64 u32 h-lo stage
#define SMEM_U32 38816
#define SMEM_BYTES (SMEM_U32*4)

#define FCS 516          // fc LDS stride

typedef _Float16 f16x8 __attribute__((ext_vector_type(8)));
typedef float    f32x4 __attribute__((ext_vector_type(4)));
typedef unsigned u32x4 __attribute__((ext_vector_type(4)));

union H16 { _Float16 f; unsigned short u; };
__device__ __forceinline__ unsigned short f16bits(_Float16 h) { H16 t; t.f = h; return t.u; }
__device__ __forceinline__ float f16val(unsigned short b) { H16 t; t.u = b; return (float)t.f; }

// split x,y into f16 hi + scaled-lo (lo = (x-hi)*2048 stays in f16 normal range)
__device__ __forceinline__ void pack2(float x, float y, unsigned& hi, unsigned& lo) {
    _Float16 hx = (_Float16)x, hy = (_Float16)y;
    _Float16 lx = (_Float16)((x - (float)hx) * 2048.0f);
    _Float16 ly = (_Float16)((y - (float)hy) * 2048.0f);
    hi = (unsigned)f16bits(hx) | ((unsigned)f16bits(hy) << 16);
    lo = (unsigned)f16bits(lx) | ((unsigned)f16bits(ly) << 16);
}

// coherent (cache-bypass) 16B load/store — agent-visible like atomics, but vector-coalesced
__device__ __forceinline__ u32x4 ld16_cohere(const void* p) {
    u32x4 v;
    asm volatile("global_load_dwordx4 %0, %1, off sc0 sc1"
                 : "=&v"(v) : "v"(p) : "memory");
    return v;
}
__device__ __forceinline__ void st16_cohere(void* p, u32x4 v) {
    asm volatile("global_store_dwordx4 %0, %1, off sc0 sc1"
                 :: "v"(p), "v"(v) : "memory");
}

// ---------------- W staging: fp32 global -> f16 hi/lo in LDS ----------------
__device__ __forceinline__ void load_w_f16(unsigned* __restrict__ sm32, float* __restrict__ b_l,
                                           const float* __restrict__ Whh,
                                           const float* __restrict__ Wih,
                                           const float* __restrict__ bias,
                                           int u0, int tid) {
    for (int r = 0; r < 48; ++r) {
        int id = tid + 256*r;            // 0..12287
        int cc = id / 384;
        int jj = id - cc*384;            // u32 index in row -> k = 2*jj
        int C  = (cc >> 3)*HH + u0 + (cc & 7);
        float2 v;
        if (jj < 256) v = ((const float2*)(Whh + (size_t)C*HH))[jj];
        else          v = ((const float2*)(Wih + (size_t)C*DIN))[jj - 256];
        unsigned hi, lo;
        pack2(v.x, v.y, hi, lo);
        sm32[W_HI_OFF + cc*RSU + jj] = hi;
        sm32[W_LO_OFF + cc*RSU + jj] = lo;
    }
    if (tid < 32) {
        int C = (tid >> 3)*HH + u0 + (tid & 7);
        b_l[tid] = bias[C];
    }
}

// ---------------- persistent LSTM kernel ----------------
// hbuf layout: [group][buf][producer ij][b 0..15][u 0..7] u16 planes (hi, lo).
// Producer writes 256B contiguous per plane; consumer gathers fully-streamed.
__global__ __launch_bounds__(256, 1)
void lstm_persist(const float* __restrict__ x, const float* __restrict__ target,
                  const float* __restrict__ h0, const float* __restrict__ c0,
                  const float* __restrict__ eWih, const float* __restrict__ eWhh,
                  const float* __restrict__ eb,
                  const float* __restrict__ dWih, const float* __restrict__ dWhh,
                  const float* __restrict__ db,
                  float* __restrict__ hs,
                  unsigned short* __restrict__ hbh,
                  unsigned short* __restrict__ hbl,
                  unsigned* __restrict__ bar)
{
    extern __shared__ unsigned sm32[];
    float* p_l = (float*)(sm32 + P_OFF);
    float* b_l = (float*)(sm32 + B_OFF);
    float* c_l = (float*)(sm32 + C_OFF);
    unsigned* hst_hi = sm32 + HST_HI;
    unsigned* hst_lo = sm32 + HST_LO;

    const int tid = (int)threadIdx.x;
    const int xcd = (int)(blockIdx.x & 7);
    const int ib  = xcd >> 1;                  // batch group 0..3 (independent)
    const int sub = xcd & 1;
    const int ij  = (int)(blockIdx.x >> 3) | (sub << 5);   // producer id 0..63
    const int b0  = ib * 16;
    const int u0  = ij * 8;
    unsigned* gflags = bar + ib*64;            // 64 monotonic per-producer flags

    load_w_f16(sm32, b_l, eWhh, eWih, eb, u0, tid);
    if (tid < 128) {
        int b = tid >> 3, u = tid & 7;
        c_l[tid] = c0[(size_t)(b0 + b)*HH + u0 + u];
    }
    // stage x for s=0 into A[.., 512..768)
    for (int r = 0; r < 4; ++r) {
        int idx4 = tid + 256*r;
        int b = idx4 >> 6, j4 = idx4 & 63;
        float4 v = ((const float4*)(x + ((size_t)b0 + b)*DIN))[j4];
        unsigned hp0, lp0, hp1, lp1;
        pack2(v.x, v.y, hp0, lp0);
        pack2(v.z, v.w, hp1, lp1);
        int o = b*RSU + 256 + 2*j4;
        sm32[A_HI_OFF + o]     = hp0;
        sm32[A_HI_OFF + o + 1] = hp1;
        sm32[A_LO_OFF + o]     = lp0;
        sm32[A_LO_OFF + o + 1] = lp1;
    }
    // h_{-1} = h0 (fp32) -> split into A[.., 0..512)
    for (int r = 0; r < 8; ++r) {
        int idx4 = tid + 256*r;
        int b = idx4 >> 7, j4 = idx4 & 127;
        float4 v = ((const float4*)(h0 + (size_t)(b0 + b)*HH))[j4];
        unsigned hp0, lp0, hp1, lp1;
        pack2(v.x, v.y, hp0, lp0);
        pack2(v.z, v.w, hp1, lp1);
        int o = b*RSU + 2*j4;
        sm32[A_HI_OFF + o]     = hp0;
        sm32[A_HI_OFF + o + 1] = hp1;
        sm32[A_LO_OFF + o]     = lp0;
        sm32[A_LO_OFF + o + 1] = lp1;
    }
    __syncthreads();

    const int lane = tid & 63;
    const int wid  = tid >> 6;
    const int m    = lane & 15;        // A row (batch) / B col (gate-col)
    const int q    = lane >> 4;        // quad
    const int ct   = wid & 1;          // col-tile (16 cols)
    const int kh   = wid >> 1;         // k-half

    const _Float16* aH = (const _Float16*)(sm32 + A_HI_OFF);
    const _Float16* aL = (const _Float16*)(sm32 + A_LO_OFF);
    const _Float16* wH = (const _Float16*)(sm32 + W_HI_OFF);
    const _Float16* wL = (const _Float16*)(sm32 + W_LO_OFF);
    const int aoff = m*RSH + q*8;
    const int woff = (ct*16 + m)*RSH + q*8;

    // carried x-part partials for the upcoming step
    f32x4 Ahh = {0.f,0.f,0.f,0.f}, Ahl = {0.f,0.f,0.f,0.f}, Alh = {0.f,0.f,0.f,0.f};
    // pre-loop: x-GEMM for s=0 (k-steps 16..23, kh half)
    {
        const int xs0 = 16 + kh*4;
        #pragma unroll
        for (int i = 0; i < 4; ++i) {
            const int o = (xs0 + i) * 32;
            f16x8 ah = *(const f16x8*)(aH + aoff + o);
            f16x8 al = *(const f16x8*)(aL + aoff + o);
            f16x8 wh = *(const f16x8*)(wH + woff + o);
            f16x8 wl = *(const f16x8*)(wL + woff + o);
            Ahh = __builtin_amdgcn_mfma_f32_16x16x32_f16(ah, wh, Ahh, 0, 0, 0);
            Ahl = __builtin_amdgcn_mfma_f32_16x16x32_f16(ah, wl, Ahl, 0, 0, 0);
            Alh = __builtin_amdgcn_mfma_f32_16x16x32_f16(al, wh, Alh, 0, 0, 0);
        }
    }

    for (int s = 0; s < 1024; ++s) {
        // ---- 1. poll + gather h_{s-1} (single-hop consume path) ----
        if (s > 0) {
            if (tid < 64) {
                while (true) {
                    unsigned v = __hip_atomic_load(&gflags[tid], __ATOMIC_RELAXED,
                                                   __HIP_MEMORY_SCOPE_AGENT);
                    if (__ballot(v >= (unsigned)s) == ~0ull) break;
                    __builtin_amdgcn_s_sleep(1);
                }
            }
            __syncthreads();
            const int buf = s & 1;
            const unsigned short* srcH = hbh + ((size_t)ib*2 + buf)*8192;
            const unsigned short* srcL = hbl + ((size_t)ib*2 + buf)*8192;
            u32x4 hv0 = ld16_cohere((const u32x4*)srcH + tid);
            u32x4 hv1 = ld16_cohere((const u32x4*)srcH + tid + 256);
            u32x4 hv2 = ld16_cohere((const u32x4*)srcH + tid + 512);
            u32x4 hv3 = ld16_cohere((const u32x4*)srcH + tid + 768);
            u32x4 lv0 = ld16_cohere((const u32x4*)srcL + tid);
            u32x4 lv1 = ld16_cohere((const u32x4*)srcL + tid + 256);
            u32x4 lv2 = ld16_cohere((const u32x4*)srcL + tid + 512);
            u32x4 lv3 = ld16_cohere((const u32x4*)srcL + tid + 768);
            asm volatile("s_waitcnt vmcnt(0)"
                         : "+v"(hv0), "+v"(hv1), "+v"(hv2), "+v"(hv3),
                           "+v"(lv0), "+v"(lv1), "+v"(lv2), "+v"(lv3) :: "memory");
            // chunk c = ijp*16 + b  ->  A row b, dwords ijp*4..+3
            {
                int c, b, jp;
                c = tid;       b = c & 15; jp = c >> 4;
                *(u32x4*)(sm32 + A_HI_OFF + b*RSU + jp*4) = hv0;
                *(u32x4*)(sm32 + A_LO_OFF + b*RSU + jp*4) = lv0;
                c = tid + 256; b = c & 15; jp = c >> 4;
                *(u32x4*)(sm32 + A_HI_OFF + b*RSU + jp*4) = hv1;
                *(u32x4*)(sm32 + A_LO_OFF + b*RSU + jp*4) = lv1;
                c = tid + 512; b = c & 15; jp = c >> 4;
                *(u32x4*)(sm32 + A_HI_OFF + b*RSU + jp*4) = hv2;
                *(u32x4*)(sm32 + A_LO_OFF + b*RSU + jp*4) = lv2;
                c = tid + 768; b = c & 15; jp = c >> 4;
                *(u32x4*)(sm32 + A_HI_OFF + b*RSU + jp*4) = hv3;
                *(u32x4*)(sm32 + A_LO_OFF + b*RSU + jp*4) = lv3;
            }
            __syncthreads();
        }

        // ---- 2. h-part GEMM (k-steps 0..15) on top of carried x partials ----
        f32x4 Chh = Ahh, Chl = Ahl, Clh = Alh;
        {
            const int hs0 = kh * 8;
            #pragma unroll
            for (int i = 0; i < 8; ++i) {
                const int o = (hs0 + i) * 32;
                f16x8 ah = *(const f16x8*)(aH + aoff + o);
                f16x8 al = *(const f16x8*)(aL + aoff + o);
                f16x8 wh = *(const f16x8*)(wH + woff + o);
                f16x8 wl = *(const f16x8*)(wL + woff + o);
                Chh = __builtin_amdgcn_mfma_f32_16x16x32_f16(ah, wh, Chh, 0, 0, 0);
                Chl = __builtin_amdgcn_mfma_f32_16x16x32_f16(ah, wl, Chl, 0, 0, 0);
                Clh = __builtin_amdgcn_mfma_f32_16x16x32_f16(al, wh, Clh, 0, 0, 0);
            }
        }
        {
            float4 C;
            const float sc = 1.0f / 2048.0f;
            C.x = Chh[0] + (Chl[0] + Clh[0]) * sc;
            C.y = Chh[1] + (Chl[1] + Clh[1]) * sc;
            C.z = Chh[2] + (Chl[2] + Clh[2]) * sc;
            C.w = Chh[3] + (Chl[3] + Clh[3]) * sc;
            *(float4*)(p_l + (ct*2 + kh)*320 + m*20 + q*4) = C;
        }
        __syncthreads();

        // ---- 3. elementwise LSTM update -> LDS h-stage ----
        if (tid < 128) {
            int b = tid >> 3, u = tid & 7;
            float gi = p_l[      u*20 + b] + p_l[320 +      u*20 + b] + b_l[u];
            float gf = p_l[(8+u)*20 + b] + p_l[320 + (8+u)*20 + b] + b_l[8 + u];
            float gg = p_l[640 +   u*20 + b] + p_l[960 +      u*20 + b] + b_l[16 + u];
            float go = p_l[640 + (8+u)*20 + b] + p_l[960 + (8+u)*20 + b] + b_l[24 + u];
            float ii = 1.f / (1.f + expf(-gi));
            float ff = 1.f / (1.f + expf(-gf));
            float g2 = tanhf(gg);
            float oo = 1.f / (1.f + expf(-go));
            float c  = ff * c_l[tid] + ii * g2;
            c_l[tid] = c;
            float hval = oo * tanhf(c);
            _Float16 hh = (_Float16)hval;
            _Float16 hl = (_Float16)((hval - (float)hh) * 2048.0f);
            ((unsigned short*)hst_hi)[tid] = f16bits(hh);   // tid = b*8+u
            ((unsigned short*)hst_lo)[tid] = f16bits(hl);
        }
        __syncthreads();

        const int ns = s + 1;

        // ---- 4a. wave0: publish (contiguous 256B/plane) + flag ----
        if (tid < 64) {
            const int nbuf = (s & 1) ^ 1;
            if (tid < 32) {
                unsigned short* dst = (tid < 16)
                    ? hbh + ((size_t)ib*2 + nbuf)*8192 + (size_t)ij*128 + (tid & 15)*8
                    : hbl + ((size_t)ib*2 + nbuf)*8192 + (size_t)ij*128 + (tid & 15)*8;
                u32x4 v = (tid < 16) ? *(const u32x4*)(hst_hi + (tid & 15)*4)
                                     : *(const u32x4*)(hst_lo + (tid & 15)*4);
                st16_cohere(dst, v);
            }
            asm volatile("s_waitcnt vmcnt(0)" ::: "memory");
            if (tid == 0)
                __hip_atomic_store(&gflags[ij], (unsigned)ns,
                                   __ATOMIC_RELAXED, __HIP_MEMORY_SCOPE_AGENT);
        }

        // ---- 4b. waves1-3: stage x for step ns ----
        if (tid >= 64 && ns < 1024) {
            int t = tid - 64;
            if (ns == 512) {
                for (int r = 0; r < 6; ++r) {
                    int idx4 = t + 192*r;
                    if (idx4 < 1024) {
                        int b = idx4 >> 6, j4 = idx4 & 63;
                        int o = b*RSU + 256 + 2*j4;
                        sm32[A_HI_OFF + o]     = 0u;
                        sm32[A_HI_OFF + o + 1] = 0u;
                        sm32[A_LO_OFF + o]     = 0u;
                        sm32[A_LO_OFF + o + 1] = 0u;
                    }
                }
            } else {
                const float* src = (ns < 512) ? x + ((size_t)ns*BB + b0)*DIN
                                              : target + ((size_t)(ns - 513)*BB + b0)*DOUT;
                for (int r = 0; r < 6; ++r) {
                    int idx4 = t + 192*r;
                    if (idx4 < 1024) {
                        int b = idx4 >> 6, j4 = idx4 & 63;
                        float4 v = ((const float4*)(src + (size_t)b*DIN))[j4];
                        unsigned hp0, lp0, hp1, lp1;
                        pack2(v.x, v.y, hp0, lp0);
                        pack2(v.z, v.w, hp1, lp1);
                        int o = b*RSU + 256 + 2*j4;
                        sm32[A_HI_OFF + o]     = hp0;
                        sm32[A_HI_OFF + o + 1] = hp1;
                        sm32[A_LO_OFF + o]     = lp0;
                        sm32[A_LO_OFF + o + 1] = lp1;
                    }
                }
            }
        }

        // ---- 4c. waves2-3: hs output (reconstructed; == what consumers see) ----
        if (tid >= 128 && s >= 512) {
            int t = tid - 128;
            int b = t >> 3, u = t & 7;
            float h = f16val(((unsigned short*)hst_hi)[t])
                    + f16val(((unsigned short*)hst_lo)[t]) * (1.0f/2048.0f);
            hs[((size_t)(s - 512)*BB + (b0 + b))*HH + (u0 + u)] = h;
        }

        // ---- 4d. decoder W swap (once) ----
        if (s == 511) load_w_f16(sm32, b_l, dWhh, dWih, db, u0, tid);
        __syncthreads();

        // ---- 5. x-part GEMM for step ns (overlaps peers' publish->flag latency) ----
        if (ns < 1024) {
            f32x4 Xhh = {0.f,0.f,0.f,0.f}, Xhl = {0.f,0.f,0.f,0.f}, Xlh = {0.f,0.f,0.f,0.f};
            const int xs0 = 16 + kh*4;
            #pragma unroll
            for (int i = 0; i < 4; ++i) {
                const int o = (xs0 + i) * 32;
                f16x8 ah = *(const f16x8*)(aH + aoff + o);
                f16x8 al = *(const f16x8*)(aL + aoff + o);
                f16x8 wh = *(const f16x8*)(wH + woff + o);
                f16x8 wl = *(const f16x8*)(wL + woff + o);
                Xhh = __builtin_amdgcn_mfma_f32_16x16x32_f16(ah, wh, Xhh, 0, 0, 0);
                Xhl = __builtin_amdgcn_mfma_f32_16x16x32_f16(ah, wl, Xhl, 0, 0, 0);
                Xlh = __builtin_amdgcn_mfma_f32_16x16x32_f16(al, wh, Xlh, 0, 0, 0);
            }
            Ahh = Xhh; Ahl = Xhl; Alh = Xlh;
        }
    }
}

// ---------------- FC (logits) kernel ----------------
__global__ __launch_bounds__(256, 1)
void fc_kernel(const float* __restrict__ hs, const float* __restrict__ W,
               const float* __restrict__ bias, float* __restrict__ out)
{
    extern __shared__ float sm[];
    float* hs_l = sm;              // 16 x FCS
    float* w_l  = sm + 16*FCS;     // 32 x FCS

    const int tid = (int)threadIdx.x;
    const int rb = (int)(blockIdx.x >> 3);
    const int cb = (int)(blockIdx.x & 7);

    for (int r = 0; r < 8; ++r) {
        int id = tid + 256*r;
        int b = id >> 7, j = id & 127;
        float4 v = ((const float4*)(hs + (size_t)(rb*16 + b)*HH))[j];
        *(float4*)(hs_l + b*FCS + 4*j) = v;
    }
    for (int r = 0; r < 16; ++r) {
        int id = tid + 256*r;
        int c = id >> 7, j = id & 127;
        float4 v = ((const float4*)(W + (size_t)(cb*32 + c)*HH))[j];
        *(float4*)(w_l + c*FCS + 4*j) = v;
    }
    __syncthreads();

    const int kc = tid & 7, bt = (tid >> 3) & 3, ct = tid >> 5;
    float acc[4][4] = {};
    const float* ap = hs_l + (bt*4)*FCS + 4*kc;
    const float* wp = w_l  + (ct*4)*FCS + 4*kc;
    #pragma unroll 4
    for (int i = 0; i < 16; ++i) {
        float4 av[4], wv[4];
        #pragma unroll
        for (int q = 0; q < 4; ++q) av[q] = *(const float4*)(ap + q*FCS + 32*i);
        #pragma unroll
        for (int q = 0; q < 4; ++q) wv[q] = *(const float4*)(wp + q*FCS + 32*i);
        #pragma unroll
        for (int b2 = 0; b2 < 4; ++b2)
            #pragma unroll
            for (int c2 = 0; c2 < 4; ++c2)
                acc[b2][c2] += av[b2].x*wv[c2].x + av[b2].y*wv[c2].y
                             + av[b2].z*wv[c2].z + av[b2].w*wv[c2].w;
    }
    #pragma unroll
    for (int b2 = 0; b2 < 4; ++b2)
        #pragma unroll
        for (int c2 = 0; c2 < 4; ++c2) {
            float v = acc[b2][c2];
            v += __shfl_xor(v, 1, 64);
            v += __shfl_xor(v, 2, 64);
            v += __shfl_xor(v, 4, 64);
            acc[b2][c2] = v;
        }
    if (kc == 0) {
        #pragma unroll
        for (int b2 = 0; b2 < 4; ++b2)
            #pragma unroll
            for (int c2 = 0; c2 < 4; ++c2) {
                int row = rb*16 + bt*4 + b2;
                int col = cb*32 + ct*4 + c2;
                out[(size_t)row*DOUT + col] = acc[b2][c2] + bias[col];
            }
    }
}

// ---------------- in-place softmax over last dim (256) ----------------
__global__ __launch_bounds__(256, 1)
void softmax_kernel(float* __restrict__ out)
{
    int row  = (int)blockIdx.x * 4 + ((int)threadIdx.x >> 6);
    int lane = (int)threadIdx.x & 63;
    float4 v = ((const float4*)(out + (size_t)row*DOUT))[lane];
    float m = fmaxf(fmaxf(v.x, v.y), fmaxf(v.z, v.w));
    #pragma unroll
    for (int d = 1; d < 64; d <<= 1) m = fmaxf(m, __shfl_xor(m, d, 64));
    float ex = expf(v.x - m), ey = expf(v.y - m), ez = expf(v.z - m), ew = expf(v.w - m);
    float ssum = ex + ey + ez + ew;
    #pragma unroll
    for (int d = 1; d < 64; d <<= 1) ssum += __shfl_xor(ssum, d, 64);
    float inv = 1.f / ssum;
    float4 o = make_float4(ex*inv, ey*inv, ez*inv, ew*inv);
    ((float4*)(out + (size_t)row*DOUT))[lane] = o;
}

// ---------------- flag init (ws is poisoned 0xAA before every call) ----------------
__global__ void init_kernel(unsigned* __restrict__ bar)
{
    bar[threadIdx.x] = 0u;
}

// ---------------- launch ----------------
extern "C" void kernel_launch(void* const* d_in, const int* in_sizes, int n_in,
                              void* d_out, int out_size, void* d_ws, size_t ws_size,
                              hipStream_t stream) {
    (void)in_sizes; (void)n_in; (void)out_size; (void)ws_size;
    const float* x      = (const float*)d_in[0];
    const float* target = (const float*)d_in[1];
    const float* h0     = (const float*)d_in[2];
    const float* c0     = (const float*)d_in[3];
    const float* eWih   = (const float*)d_in[4];
    const float* eWhh   = (const float*)d_in[5];
    const float* eb     = (const float*)d_in[6];
    const float* dWih   = (const float*)d_in[7];
    const float* dWhh   = (const float*)d_in[8];
    const float* db     = (const float*)d_in[9];
    const float* fcW    = (const float*)d_in[10];
    const float* fcb    = (const float*)d_in[11];
    float* out = (float*)d_out;

    unsigned* bar = (unsigned*)d_ws;                        // 1024 u32 flags
    float* hs = (float*)d_ws + 1024;                        // [T*B*H] decoder hidden
    unsigned short* hbh = (unsigned short*)(hs + (size_t)TT*BB*HH);  // 4*2*8192 u16 hi
    unsigned short* hbl = hbh + (size_t)4*2*8192;                    // lo plane

    init_kernel<<<dim3(1), dim3(1024), 0, stream>>>(bar);

    lstm_persist<<<dim3(256), dim3(256), SMEM_BYTES, stream>>>(
        x, target, h0, c0, eWih, eWhh, eb, dWih, dWhh, db, hs, hbh, hbl, bar);

    size_t lds_fc = (size_t)(48*FCS) * sizeof(float);       // ~99 KB
    fc_kernel<<<dim3(16384), dim3(256), lds_fc, stream>>>(hs, fcW, fcb, out);

    softmax_kernel<<<dim3(8192), dim3(256), 0, stream>>>(out);
}